// Round 7
// baseline (76.460 us; speedup 1.0000x reference)
//
#include <hip/hip_runtime.h>
#include <hip/hip_bf16.h>
#include <math.h>

#define BB 4
#define NTOK 4096
#define CC 256
#define NH 4
#define HD 64
#define CKV 128

typedef _Float16 half8 __attribute__((ext_vector_type(8)));
typedef _Float16 half4 __attribute__((ext_vector_type(4)));
typedef _Float16 half2v __attribute__((ext_vector_type(2)));
typedef float    f32x4 __attribute__((ext_vector_type(4)));

__device__ __forceinline__ half2v pkrtz(float a, float b) {
  return __builtin_bit_cast(half2v, __builtin_amdgcn_cvt_pkrtz(a, b));
}
// row-swizzled LDS index for 64-half rows (uses row bits 0-2)
__device__ __forceinline__ int swzi(int row, int d) {
  return row * 64 + (d ^ ((row & 7) << 3));
}
// Vt swizzle: staging writes rows in pairs (2l, 2l+1) -> use row bits 1-3
__device__ __forceinline__ int swzv(int row, int d) {
  return row * 64 + (d ^ (((row >> 1) & 7) << 3));
}
__device__ __forceinline__ f32x4 mfma16(half8 a, half8 b, f32x4 c) {
  return __builtin_amdgcn_mfma_f32_16x16x32_f16(a, b, c, 0, 0, 0);
}

// ---------------------------------------------------------------------------
// pre_all: [0,1024) transpose+cast x -> Xt fp16 [b][p][c]
//          [1024,2048) same for y -> Yt
//          [2048,2688) weight prep (BN fold, fp16 cast)
// ---------------------------------------------------------------------------
__global__ __launch_bounds__(256) void pre_all(
    const float* __restrict__ x, const float* __restrict__ y,
    const float* __restrict__ qw, const float* __restrict__ qg_, const float* __restrict__ qb,
    const float* __restrict__ qm, const float* __restrict__ qv,
    const float* __restrict__ kw, const float* __restrict__ kg_, const float* __restrict__ kb,
    const float* __restrict__ km, const float* __restrict__ kvv,
    const float* __restrict__ pw,
    _Float16* __restrict__ Xt, _Float16* __restrict__ Yt,
    _Float16* __restrict__ qWh, float* __restrict__ qB2,
    _Float16* __restrict__ kWh, float* __restrict__ kB2,
    _Float16* __restrict__ pWh)
{
  const int id = blockIdx.x;
  __shared__ float T[64][65];
  const int t = threadIdx.x;
  if (id < 2048) {
    const float* X   = (id < 1024) ? x  : y;
    _Float16*   XT   = (id < 1024) ? Xt : Yt;
    const int i = id & 1023;
    const int pt = i & 63, ct = (i >> 6) & 3, b = i >> 8;
    const float* Xb = X + (size_t)b * CC * NTOK + (size_t)ct * 64 * NTOK + pt * 64;
    const int cr = t >> 4, pc = (t & 15) * 4;
    #pragma unroll
    for (int k = 0; k < 4; ++k) {
      float4 v = *(const float4*)&Xb[(size_t)(cr + k * 16) * NTOK + pc];
      T[cr + k * 16][pc]     = v.x;  T[cr + k * 16][pc + 1] = v.y;
      T[cr + k * 16][pc + 2] = v.z;  T[cr + k * 16][pc + 3] = v.w;
    }
    __syncthreads();
    _Float16* Ot = XT + (size_t)b * NTOK * CC + (size_t)(pt * 64) * CC + ct * 64;
    #pragma unroll
    for (int k = 0; k < 2; ++k) {
      int u = t + k * 256;
      int p = u >> 3, ch = u & 7;
      half8 h;
      #pragma unroll
      for (int j = 0; j < 8; ++j) h[j] = (_Float16)T[ch * 8 + j][p];
      *(half8*)&Ot[(size_t)p * CC + ch * 8] = h;
    }
  } else {
    const int r = id - 2048;
    const int c = t;
    if (r < 256) {
      float g = qg_[r] * rsqrtf(qv[r] + 1e-5f);
      qWh[r * 256 + c] = (_Float16)(qw[r * 256 + c] * g);
      if (c == 0) qB2[r] = qb[r] - qm[r] * g;
    } else if (r < 384) {
      int o = r - 256;
      float g = kg_[o] * rsqrtf(kvv[o] + 1e-5f);
      kWh[o * 256 + c] = (_Float16)(kw[o * 256 + c] * g);
      if (c == 0) kB2[o] = kb[o] - km[o] * g;
    } else if (r < 640) {
      int o = r - 384;
      pWh[o * 256 + c] = (_Float16)pw[o * 256 + c];
    }
  }
}

// ---------------------------------------------------------------------------
// merged conv1x1+BN+SiLU fp16 MFMA GEMM (q conv: blockIdx.y<4, kv: 4..5)
// ---------------------------------------------------------------------------
__global__ __launch_bounds__(256) void conv_mfma_all(
    const _Float16* __restrict__ Xt, const _Float16* __restrict__ Yt,
    const _Float16* __restrict__ qWh, const float* __restrict__ qB2,
    const _Float16* __restrict__ kWh, const float* __restrict__ kB2,
    _Float16* __restrict__ qout, _Float16* __restrict__ kvout)
{
  const int ptile = blockIdx.x, oy = blockIdx.y, b = blockIdx.z;
  const bool isq = oy < 4;
  const _Float16* A  = isq ? Xt : Yt;
  const _Float16* W  = isq ? qWh : kWh;
  const float*    B2 = isq ? qB2 : kB2;
  _Float16*       Y  = isq ? qout : kvout;
  const int otile = isq ? oy : oy - 4;
  const int COUT  = isq ? 256 : 128;

  __shared__ _Float16 Xs[128 * 64];
  __shared__ _Float16 Ws[64 * 64];
  const int t = threadIdx.x, wave = t >> 6, lane = t & 63;
  const int lm = lane & 15, lg = lane >> 4;
  const _Float16* Xb = A + (size_t)b * NTOK * CC + (size_t)ptile * 128 * CC;
  const _Float16* Wb = W + otile * 64 * 256;
  f32x4 acc[2][4];
  #pragma unroll
  for (int m = 0; m < 2; ++m)
    #pragma unroll
    for (int n = 0; n < 4; ++n) acc[m][n] = (f32x4){0.f, 0.f, 0.f, 0.f};

  for (int c0 = 0; c0 < 256; c0 += 64) {
    __syncthreads();
    #pragma unroll
    for (int i = 0; i < 4; ++i) {
      int u = t + i * 256; int p = u >> 3, ch = u & 7;
      *(half8*)&Xs[swzi(p, ch * 8)] = *(const half8*)&Xb[(size_t)p * 256 + c0 + ch * 8];
    }
    #pragma unroll
    for (int i = 0; i < 2; ++i) {
      int u = t + i * 256; int o = u >> 3, ch = u & 7;
      *(half8*)&Ws[swzi(o, ch * 8)] = *(const half8*)&Wb[o * 256 + c0 + ch * 8];
    }
    __syncthreads();
    #pragma unroll
    for (int kh = 0; kh < 2; ++kh) {
      half8 af[2], bf[4];
      #pragma unroll
      for (int m = 0; m < 2; ++m) af[m] = *(half8*)&Xs[swzi(wave * 32 + m * 16 + lm, kh * 32 + lg * 8)];
      #pragma unroll
      for (int n = 0; n < 4; ++n) bf[n] = *(half8*)&Ws[swzi(n * 16 + lm, kh * 32 + lg * 8)];
      #pragma unroll
      for (int m = 0; m < 2; ++m)
        #pragma unroll
        for (int n = 0; n < 4; ++n)
          acc[m][n] = mfma16(af[m], bf[n], acc[m][n]);
    }
  }
  _Float16* Yb = Y + (size_t)b * COUT * NTOK;
  #pragma unroll
  for (int m = 0; m < 2; ++m)
    #pragma unroll
    for (int n = 0; n < 4; ++n) {
      int o = otile * 64 + n * 16 + lm;
      float b2 = B2[o];
      float r[4];
      #pragma unroll
      for (int rr = 0; rr < 4; ++rr) {
        float v = acc[m][n][rr] + b2;
        r[rr] = v / (1.f + __expf(-v));
      }
      half2v p0 = pkrtz(r[0], r[1]);
      half2v p1 = pkrtz(r[2], r[3]);
      half4 h; h[0]=p0[0]; h[1]=p0[1]; h[2]=p1[0]; h[3]=p1[1];
      int p = ptile * 128 + wave * 32 + m * 16 + lg * 4;
      *(half4*)&Yb[(size_t)o * NTOK + p] = h;
    }
}

// ---------------------------------------------------------------------------
// fp16 MFMA flash attention v4: swapped-operand, double-buffered K/Vt,
// ONE barrier per KV-tile. 64 q-rows/block (16/wave), KVBLK=64.
// ---------------------------------------------------------------------------
__global__ __launch_bounds__(256) void attn_mfma4(
    const _Float16* __restrict__ Q,   // [b][256*4096] fp16 scrambled conv out
    const _Float16* __restrict__ KV,  // [b][128*4096]
    _Float16* __restrict__ O)         // flat [b][h][n][d] fp16
{
  const int nt = blockIdx.x, hh = blockIdx.y, b = blockIdx.z;
  const int n0 = nt * 64;
  const int t = threadIdx.x, wave = t >> 6, lane = t & 63;
  const int lm = lane & 15, lg = lane >> 4;
  const int wq = wave * 16;
  const float SCL = 0.125f * 1.44269504f;  // scale * log2(e)

  __shared__ _Float16 Kl[2][64 * 64];
  __shared__ _Float16 Vt[2][64 * 64];
  __shared__ _Float16 Pl[64 * 64];

  const _Float16* Qb  = Q  + (size_t)b * (CC * NTOK)  + hh * 64;
  const _Float16* KVb = KV + (size_t)b * (CKV * NTOK) + hh * 64;

  // Q fragment: this wave's 16 rows (q = wq + lm)
  half8 qf[2];
  {
    int n = n0 + wq + lm;
    const _Float16* src = Qb + (n >> 4) * 4096 + (n & 15) * 256;
    qf[0] = *(const half8*)(src + lg * 8);
    qf[1] = *(const half8*)(src + 32 + lg * 8);
  }

  half8 ones;
  #pragma unroll
  for (int j = 0; j < 8; ++j) ones[j] = (_Float16)1.f;

  f32x4 acc[4], accl;
  float m_run = -1e30f;
  #pragma unroll
  for (int dg = 0; dg < 4; ++dg) acc[dg] = (f32x4){0.f, 0.f, 0.f, 0.f};
  accl = (f32x4){0.f, 0.f, 0.f, 0.f};

  const int dvp = (t & 31) * 2, kgv = t >> 5;  // V prefetch unit
  half8 kreg[2];
  unsigned int vreg[8];

  auto PREFETCH = [&](int mt) {
    #pragma unroll
    for (int it = 0; it < 2; ++it) {
      int s = t + it * 256; int key = s >> 3, ch = s & 7;
      kreg[it] = *(const half8*)(KVb + (size_t)(mt * 8 + (key >> 3)) * 4096 + (key & 7) * 512 + ch * 8);
    }
    const _Float16* vsrc = KVb + (size_t)(mt * 8 + kgv) * 4096 + 256 + dvp;
    #pragma unroll
    for (int j = 0; j < 8; ++j)
      vreg[j] = *(const unsigned int*)(vsrc + j * 512);
  };
  auto STORE_LDS = [&](int buf) {
    #pragma unroll
    for (int it = 0; it < 2; ++it) {
      int s = t + it * 256; int key = s >> 3, ch = s & 7;
      *(half8*)&Kl[buf][swzi(key, ch * 8)] = kreg[it];
    }
    half8 lo, hi;
    #pragma unroll
    for (int j = 0; j < 8; ++j) {
      half2v hv = __builtin_bit_cast(half2v, vreg[j]);
      lo[j] = hv[0]; hi[j] = hv[1];
    }
    *(half8*)&Vt[buf][swzv(dvp,     kgv * 8)] = lo;
    *(half8*)&Vt[buf][swzv(dvp + 1, kgv * 8)] = hi;
  };

  PREFETCH(0);
  STORE_LDS(0);
  __syncthreads();

  int cur = 0;
  for (int mt = 0; mt < 16; ++mt) {
    if (mt < 15) PREFETCH(mt + 1);   // global loads fly under compute

    // S^T = mfma(K, Q): lane holds S^T[k=kt*16+lg*4+r][q=lm]
    f32x4 sc[4];
    #pragma unroll
    for (int kt = 0; kt < 4; ++kt) {
      half8 kf0 = *(half8*)&Kl[cur][swzi(kt * 16 + lm, lg * 8)];
      half8 kf1 = *(half8*)&Kl[cur][swzi(kt * 16 + lm, 32 + lg * 8)];
      f32x4 z = (f32x4){0.f, 0.f, 0.f, 0.f};
      z = mfma16(kf0, qf[0], z);
      z = mfma16(kf1, qf[1], z);
      sc[kt] = z;
    }

    // row max: max3-friendly tree + 2 shuffles
    float t0 = fmaxf(fmaxf(sc[0][0], sc[0][1]), sc[0][2]);
    float t1 = fmaxf(fmaxf(sc[0][3], sc[1][0]), sc[1][1]);
    float t2 = fmaxf(fmaxf(sc[1][2], sc[1][3]), sc[2][0]);
    float t3 = fmaxf(fmaxf(sc[2][1], sc[2][2]), sc[2][3]);
    float t4 = fmaxf(fmaxf(sc[3][0], sc[3][1]), sc[3][2]);
    float tm = fmaxf(fmaxf(fmaxf(t0, t1), t2), fmaxf(fmaxf(t3, t4), sc[3][3]));
    tm *= SCL;
    tm = fmaxf(tm, __shfl_xor(tm, 16, 64));
    tm = fmaxf(tm, __shfl_xor(tm, 32, 64));
    if (__any(tm > m_run + 8.0f)) {   // defer-max THR=8 (log2 domain)
      float mnew = fmaxf(m_run, tm);
      float corr = exp2f(m_run - mnew);
      #pragma unroll
      for (int dg = 0; dg < 4; ++dg) acc[dg] *= corr;
      accl *= corr;
      m_run = mnew;
    }
    // P = exp2(s*SCL - m); one b64 write per kt into own wave's Pl rows
    int qrow = wq + lm;
    #pragma unroll
    for (int kt = 0; kt < 4; ++kt) {
      float p0 = exp2f(fmaf(sc[kt][0], SCL, -m_run));
      float p1 = exp2f(fmaf(sc[kt][1], SCL, -m_run));
      float p2 = exp2f(fmaf(sc[kt][2], SCL, -m_run));
      float p3 = exp2f(fmaf(sc[kt][3], SCL, -m_run));
      half2v a = pkrtz(p0, p1), c = pkrtz(p2, p3);
      half4 h; h[0]=a[0]; h[1]=a[1]; h[2]=c[0]; h[3]=c[1];
      *(half4*)&Pl[swzi(qrow, kt * 16 + lg * 4)] = h;
    }

    // O^T += mfma(V^T, P^T); denominator via ones-MFMA
    #pragma unroll
    for (int ka = 0; ka < 2; ++ka) {
      half8 pf = *(half8*)&Pl[swzi(wq + lm, ka * 32 + lg * 8)];
      accl = mfma16(ones, pf, accl);
      #pragma unroll
      for (int dg = 0; dg < 4; ++dg) {
        half8 vf = *(half8*)&Vt[cur][swzv(dg * 16 + lm, ka * 32 + lg * 8)];
        acc[dg] = mfma16(vf, pf, acc[dg]);
      }
    }

    if (mt < 15) STORE_LDS(cur ^ 1);  // write next tile into other buffer
    __syncthreads();                  // one barrier per tile
    cur ^= 1;
  }

  // epilogue: accl[0] = sum over all keys for q=lm
  float inv = 1.f / accl[0];
  int n = n0 + wq + lm;
  _Float16* dst = O + ((size_t)(b * NH + hh) * NTOK + n) * 64;
  #pragma unroll
  for (int dg = 0; dg < 4; ++dg) {
    half2v p0 = pkrtz(acc[dg][0] * inv, acc[dg][1] * inv);
    half2v p1 = pkrtz(acc[dg][2] * inv, acc[dg][3] * inv);
    half4 h; h[0]=p0[0]; h[1]=p0[1]; h[2]=p1[0]; h[3]=p1[1];
    *(half4*)(dst + dg * 16 + lg * 4) = h;
  }
}

// ---------------------------------------------------------------------------
// projection: fp16 MFMA, A = attout fp16 [16384][256], B = pWh [co][ci],
// D[r][co] + bias -> f32 out.
// ---------------------------------------------------------------------------
__global__ __launch_bounds__(256) void proj_mfma(
    const _Float16* __restrict__ A, const _Float16* __restrict__ Wp,
    const float* __restrict__ bias, float* __restrict__ Out)
{
  const int rtile = blockIdx.x, ctile = blockIdx.y;
  __shared__ _Float16 As[128 * 64];
  __shared__ _Float16 Ws[64 * 64];
  const int t = threadIdx.x, wave = t >> 6, lane = t & 63;
  const int lm = lane & 15, lg = lane >> 4;
  const _Float16* Ab = A + (size_t)rtile * 128 * 256;
  const _Float16* Wb = Wp + ctile * 64 * 256;
  f32x4 acc[2][4];
  #pragma unroll
  for (int m = 0; m < 2; ++m)
    #pragma unroll
    for (int n = 0; n < 4; ++n) acc[m][n] = (f32x4){0.f, 0.f, 0.f, 0.f};

  for (int c0 = 0; c0 < 256; c0 += 64) {
    __syncthreads();
    #pragma unroll
    for (int i = 0; i < 4; ++i) {
      int u = t + i * 256; int r = u >> 3, ch = u & 7;
      *(half8*)&As[swzi(r, ch * 8)] = *(const half8*)&Ab[(size_t)r * 256 + c0 + ch * 8];
    }
    #pragma unroll
    for (int i = 0; i < 2; ++i) {
      int u = t + i * 256; int o = u >> 3, ch = u & 7;
      *(half8*)&Ws[swzi(o, ch * 8)] = *(const half8*)&Wb[o * 256 + c0 + ch * 8];
    }
    __syncthreads();
    #pragma unroll
    for (int kh = 0; kh < 2; ++kh) {
      half8 af[2], bf[4];
      #pragma unroll
      for (int m = 0; m < 2; ++m) af[m] = *(half8*)&As[swzi(wave * 32 + m * 16 + lm, kh * 32 + lg * 8)];
      #pragma unroll
      for (int n = 0; n < 4; ++n) bf[n] = *(half8*)&Ws[swzi(n * 16 + lm, kh * 32 + lg * 8)];
      #pragma unroll
      for (int m = 0; m < 2; ++m)
        #pragma unroll
        for (int n = 0; n < 4; ++n)
          acc[m][n] = mfma16(af[m], bf[n], acc[m][n]);
    }
  }
  float* Ob = Out + (size_t)rtile * 128 * 256 + ctile * 64;
  #pragma unroll
  for (int n = 0; n < 4; ++n) {
    float bia = bias[ctile * 64 + n * 16 + lm];
    #pragma unroll
    for (int m = 0; m < 2; ++m)
      #pragma unroll
      for (int rr = 0; rr < 4; ++rr)
        Ob[(size_t)(wave * 32 + m * 16 + lg * 4 + rr) * 256 + n * 16 + lm] =
            acc[m][n][rr] + bia;
  }
}

// ---------------------------------------------------------------------------
extern "C" void kernel_launch(void* const* d_in, const int* in_sizes, int n_in,
                              void* d_out, int out_size, void* d_ws, size_t ws_size,
                              hipStream_t stream) {
  const float* x        = (const float*)d_in[0];
  const float* y        = (const float*)d_in[1];
  const float* q_w      = (const float*)d_in[4];
  const float* q_gamma  = (const float*)d_in[5];
  const float* q_beta   = (const float*)d_in[6];
  const float* q_mean   = (const float*)d_in[7];
  const float* q_var    = (const float*)d_in[8];
  const float* kv_w     = (const float*)d_in[9];
  const float* kv_gamma = (const float*)d_in[10];
  const float* kv_beta  = (const float*)d_in[11];
  const float* kv_mean  = (const float*)d_in[12];
  const float* kv_var   = (const float*)d_in[13];
  const float* proj_w   = (const float*)d_in[14];
  const float* proj_b   = (const float*)d_in[15];
  float* out = (float*)d_out;

  _Float16* Xt   = (_Float16*)d_ws;                   // 4M halfs
  _Float16* Yt   = Xt   + (size_t)BB * NTOK * CC;     // 4M
  _Float16* qbn  = Yt   + (size_t)BB * NTOK * CC;     // 4M
  _Float16* kvbn = qbn  + (size_t)BB * CC * NTOK;     // 2M
  _Float16* aout = kvbn + (size_t)BB * CKV * NTOK;    // 4M
  _Float16* qWh  = aout + (size_t)BB * NH * NTOK * HD;
  _Float16* kWh  = qWh + 256 * 256;
  _Float16* pWh  = kWh + 128 * 256;
  float* qB2 = (float*)(pWh + 256 * 256);
  float* kB2 = qB2 + 256;

  pre_all<<<2688, 256, 0, stream>>>(
      x, y, q_w, q_gamma, q_beta, q_mean, q_var,
      kv_w, kv_gamma, kv_beta, kv_mean, kv_var, proj_w,
      Xt, Yt, qWh, qB2, kWh, kB2, pWh);
  conv_mfma_all<<<dim3(32, 6, BB), 256, 0, stream>>>(
      Xt, Yt, qWh, qB2, kWh, kB2, qbn, kvbn);
  attn_mfma4<<<dim3(64, NH, BB), 256, 0, stream>>>(qbn, kvbn, aout);
  proj_mfma<<<dim3(128, 4), 256, 0, stream>>>(aout, pWh, proj_b, out);
}

// Round 8
// 66.013 us; speedup vs baseline: 1.1583x; 1.1583x over previous
//
#include <hip/hip_runtime.h>
#include <hip/hip_bf16.h>
#include <math.h>

#define BB 4
#define NTOK 4096
#define CC 256
#define NH 4
#define HD 64
#define CKV 128

typedef _Float16 half8 __attribute__((ext_vector_type(8)));
typedef _Float16 half4 __attribute__((ext_vector_type(4)));
typedef _Float16 half2v __attribute__((ext_vector_type(2)));
typedef float    f32x4 __attribute__((ext_vector_type(4)));
typedef unsigned int uint2v __attribute__((ext_vector_type(2)));

__device__ __forceinline__ half2v pkrtz(float a, float b) {
  return __builtin_bit_cast(half2v, __builtin_amdgcn_cvt_pkrtz(a, b));
}
// bare v_exp_f32: computes 2^x (we work in log2 domain)
__device__ __forceinline__ float exp2_fast(float x) {
  float r;
  asm("v_exp_f32 %0, %1" : "=v"(r) : "v"(x));
  return r;
}
// row-swizzled LDS index for 64-half rows (uses row bits 0-2)
__device__ __forceinline__ int swzi(int row, int d) {
  return row * 64 + (d ^ ((row & 7) << 3));
}
// Vt swizzle: staging writes rows in pairs (2l, 2l+1) -> use row bits 1-3
__device__ __forceinline__ int swzv(int row, int d) {
  return row * 64 + (d ^ (((row >> 1) & 7) << 3));
}
__device__ __forceinline__ f32x4 mfma16(half8 a, half8 b, f32x4 c) {
  return __builtin_amdgcn_mfma_f32_16x16x32_f16(a, b, c, 0, 0, 0);
}

// ---------------------------------------------------------------------------
// pre_all: [0,1024) transpose+cast x -> Xt fp16 [b][p][c]
//          [1024,2048) same for y -> Yt
//          [2048,2688) weight prep (BN fold, fp16 cast)
// ---------------------------------------------------------------------------
__global__ __launch_bounds__(256) void pre_all(
    const float* __restrict__ x, const float* __restrict__ y,
    const float* __restrict__ qw, const float* __restrict__ qg_, const float* __restrict__ qb,
    const float* __restrict__ qm, const float* __restrict__ qv,
    const float* __restrict__ kw, const float* __restrict__ kg_, const float* __restrict__ kb,
    const float* __restrict__ km, const float* __restrict__ kvv,
    const float* __restrict__ pw,
    _Float16* __restrict__ Xt, _Float16* __restrict__ Yt,
    _Float16* __restrict__ qWh, float* __restrict__ qB2,
    _Float16* __restrict__ kWh, float* __restrict__ kB2,
    _Float16* __restrict__ pWh)
{
  const int id = blockIdx.x;
  __shared__ float T[64][65];
  const int t = threadIdx.x;
  if (id < 2048) {
    const float* X   = (id < 1024) ? x  : y;
    _Float16*   XT   = (id < 1024) ? Xt : Yt;
    const int i = id & 1023;
    const int pt = i & 63, ct = (i >> 6) & 3, b = i >> 8;
    const float* Xb = X + (size_t)b * CC * NTOK + (size_t)ct * 64 * NTOK + pt * 64;
    const int cr = t >> 4, pc = (t & 15) * 4;
    #pragma unroll
    for (int k = 0; k < 4; ++k) {
      float4 v = *(const float4*)&Xb[(size_t)(cr + k * 16) * NTOK + pc];
      T[cr + k * 16][pc]     = v.x;  T[cr + k * 16][pc + 1] = v.y;
      T[cr + k * 16][pc + 2] = v.z;  T[cr + k * 16][pc + 3] = v.w;
    }
    __syncthreads();
    _Float16* Ot = XT + (size_t)b * NTOK * CC + (size_t)(pt * 64) * CC + ct * 64;
    #pragma unroll
    for (int k = 0; k < 2; ++k) {
      int u = t + k * 256;
      int p = u >> 3, ch = u & 7;
      half8 h;
      #pragma unroll
      for (int j = 0; j < 8; ++j) h[j] = (_Float16)T[ch * 8 + j][p];
      *(half8*)&Ot[(size_t)p * CC + ch * 8] = h;
    }
  } else {
    const int r = id - 2048;
    const int c = t;
    if (r < 256) {
      float g = qg_[r] * rsqrtf(qv[r] + 1e-5f);
      qWh[r * 256 + c] = (_Float16)(qw[r * 256 + c] * g);
      if (c == 0) qB2[r] = qb[r] - qm[r] * g;
    } else if (r < 384) {
      int o = r - 256;
      float g = kg_[o] * rsqrtf(kvv[o] + 1e-5f);
      kWh[o * 256 + c] = (_Float16)(kw[o * 256 + c] * g);
      if (c == 0) kB2[o] = kb[o] - km[o] * g;
    } else if (r < 640) {
      int o = r - 384;
      pWh[o * 256 + c] = (_Float16)pw[o * 256 + c];
    }
  }
}

// ---------------------------------------------------------------------------
// merged conv1x1+BN+SiLU fp16 MFMA GEMM (q conv: blockIdx.y<4, kv: 4..5)
// ---------------------------------------------------------------------------
__global__ __launch_bounds__(256) void conv_mfma_all(
    const _Float16* __restrict__ Xt, const _Float16* __restrict__ Yt,
    const _Float16* __restrict__ qWh, const float* __restrict__ qB2,
    const _Float16* __restrict__ kWh, const float* __restrict__ kB2,
    _Float16* __restrict__ qout, _Float16* __restrict__ kvout)
{
  const int ptile = blockIdx.x, oy = blockIdx.y, b = blockIdx.z;
  const bool isq = oy < 4;
  const _Float16* A  = isq ? Xt : Yt;
  const _Float16* W  = isq ? qWh : kWh;
  const float*    B2 = isq ? qB2 : kB2;
  _Float16*       Y  = isq ? qout : kvout;
  const int otile = isq ? oy : oy - 4;
  const int COUT  = isq ? 256 : 128;

  __shared__ _Float16 Xs[128 * 64];
  __shared__ _Float16 Ws[64 * 64];
  const int t = threadIdx.x, wave = t >> 6, lane = t & 63;
  const int lm = lane & 15, lg = lane >> 4;
  const _Float16* Xb = A + (size_t)b * NTOK * CC + (size_t)ptile * 128 * CC;
  const _Float16* Wb = W + otile * 64 * 256;
  f32x4 acc[2][4];
  #pragma unroll
  for (int m = 0; m < 2; ++m)
    #pragma unroll
    for (int n = 0; n < 4; ++n) acc[m][n] = (f32x4){0.f, 0.f, 0.f, 0.f};

  for (int c0 = 0; c0 < 256; c0 += 64) {
    __syncthreads();
    #pragma unroll
    for (int i = 0; i < 4; ++i) {
      int u = t + i * 256; int p = u >> 3, ch = u & 7;
      *(half8*)&Xs[swzi(p, ch * 8)] = *(const half8*)&Xb[(size_t)p * 256 + c0 + ch * 8];
    }
    #pragma unroll
    for (int i = 0; i < 2; ++i) {
      int u = t + i * 256; int o = u >> 3, ch = u & 7;
      *(half8*)&Ws[swzi(o, ch * 8)] = *(const half8*)&Wb[o * 256 + c0 + ch * 8];
    }
    __syncthreads();
    #pragma unroll
    for (int kh = 0; kh < 2; ++kh) {
      half8 af[2], bf[4];
      #pragma unroll
      for (int m = 0; m < 2; ++m) af[m] = *(half8*)&Xs[swzi(wave * 32 + m * 16 + lm, kh * 32 + lg * 8)];
      #pragma unroll
      for (int n = 0; n < 4; ++n) bf[n] = *(half8*)&Ws[swzi(n * 16 + lm, kh * 32 + lg * 8)];
      #pragma unroll
      for (int m = 0; m < 2; ++m)
        #pragma unroll
        for (int n = 0; n < 4; ++n)
          acc[m][n] = mfma16(af[m], bf[n], acc[m][n]);
    }
  }
  _Float16* Yb = Y + (size_t)b * COUT * NTOK;
  #pragma unroll
  for (int m = 0; m < 2; ++m)
    #pragma unroll
    for (int n = 0; n < 4; ++n) {
      int o = otile * 64 + n * 16 + lm;
      float b2 = B2[o];
      float r[4];
      #pragma unroll
      for (int rr = 0; rr < 4; ++rr) {
        float v = acc[m][n][rr] + b2;
        r[rr] = v / (1.f + __expf(-v));
      }
      half2v p0 = pkrtz(r[0], r[1]);
      half2v p1 = pkrtz(r[2], r[3]);
      half4 h; h[0]=p0[0]; h[1]=p0[1]; h[2]=p1[0]; h[3]=p1[1];
      int p = ptile * 128 + wave * 32 + m * 16 + lg * 4;
      *(half4*)&Yb[(size_t)o * NTOK + p] = h;
    }
}

// ---------------------------------------------------------------------------
// fp16 MFMA flash attention v5: 8 waves / 128 q-rows per block, swapped
// operands, dbuf K/Vt, 1 barrier/tile, inline-asm v_exp.
// ---------------------------------------------------------------------------
__global__ __launch_bounds__(512) void attn_mfma5(
    const _Float16* __restrict__ Q,   // [b][256*4096] fp16 scrambled conv out
    const _Float16* __restrict__ KV,  // [b][128*4096]
    _Float16* __restrict__ O)         // flat [b][h][n][d] fp16
{
  const int nt = blockIdx.x, hh = blockIdx.y, b = blockIdx.z;
  const int n0 = nt * 128;
  const int t = threadIdx.x, wave = t >> 6, lane = t & 63;
  const int lm = lane & 15, lg = lane >> 4;
  const int wq = wave * 16;
  const float SCL = 0.125f * 1.44269504f;  // scale * log2(e)

  __shared__ _Float16 Kl[2][64 * 64];
  __shared__ _Float16 Vt[2][64 * 64];
  __shared__ _Float16 Pl[128 * 64];

  const _Float16* Qb  = Q  + (size_t)b * (CC * NTOK)  + hh * 64;
  const _Float16* KVb = KV + (size_t)b * (CKV * NTOK) + hh * 64;

  // Q fragment: this wave's 16 rows (q = wq + lm)
  half8 qf[2];
  {
    int n = n0 + wq + lm;
    const _Float16* src = Qb + (n >> 4) * 4096 + (n & 15) * 256;
    qf[0] = *(const half8*)(src + lg * 8);
    qf[1] = *(const half8*)(src + 32 + lg * 8);
  }

  half8 ones;
  #pragma unroll
  for (int j = 0; j < 8; ++j) ones[j] = (_Float16)1.f;

  f32x4 acc[4], accl;
  float m_run = -1e30f;
  #pragma unroll
  for (int dg = 0; dg < 4; ++dg) acc[dg] = (f32x4){0.f, 0.f, 0.f, 0.f};
  accl = (f32x4){0.f, 0.f, 0.f, 0.f};

  // staging assignments (512 threads)
  const int kkey = t >> 3, kch = t & 7;          // K: 1 half8 per thread
  const int dvp = (t & 31) * 2, kgv = t >> 5;    // V: 4 dwords per thread (kgv 0..15)
  const _Float16* kp = KVb + (size_t)(kkey >> 3) * 4096 + (kkey & 7) * 512 + kch * 8;
  const _Float16* vp = KVb + (size_t)(kgv >> 1) * 4096 + (kgv & 1) * 4 * 512 + 256 + dvp;

  half8 kreg;
  unsigned int vreg[4];

  auto PREFETCH = [&]() {
    kreg = *(const half8*)kp;
    #pragma unroll
    for (int j = 0; j < 4; ++j)
      vreg[j] = *(const unsigned int*)(vp + j * 512);
    kp += 8 * 4096;  // next KV tile
    vp += 8 * 4096;
  };
  auto STORE_LDS = [&](int buf) {
    *(half8*)&Kl[buf][swzi(kkey, kch * 8)] = kreg;
    // pack 4 dwords -> row dvp (low halves) and dvp+1 (high halves)
    unsigned int lo0 = (vreg[0] & 0xffffu) | (vreg[1] << 16);
    unsigned int lo1 = (vreg[2] & 0xffffu) | (vreg[3] << 16);
    unsigned int hi0 = (vreg[0] >> 16) | (vreg[1] & 0xffff0000u);
    unsigned int hi1 = (vreg[2] >> 16) | (vreg[3] & 0xffff0000u);
    *(uint2v*)&Vt[buf][swzv(dvp,     kgv * 4)] = (uint2v){lo0, lo1};
    *(uint2v*)&Vt[buf][swzv(dvp + 1, kgv * 4)] = (uint2v){hi0, hi1};
  };

  PREFETCH();
  STORE_LDS(0);
  __syncthreads();

  int cur = 0;
  for (int mt = 0; mt < 16; ++mt) {
    if (mt < 15) PREFETCH();   // global loads fly under compute

    // S^T = mfma(K, Q): lane holds S^T[k=kt*16+lg*4+r][q=lm]
    f32x4 sc[4];
    #pragma unroll
    for (int kt = 0; kt < 4; ++kt) {
      half8 kf0 = *(half8*)&Kl[cur][swzi(kt * 16 + lm, lg * 8)];
      half8 kf1 = *(half8*)&Kl[cur][swzi(kt * 16 + lm, 32 + lg * 8)];
      f32x4 z = (f32x4){0.f, 0.f, 0.f, 0.f};
      z = mfma16(kf0, qf[0], z);
      z = mfma16(kf1, qf[1], z);
      sc[kt] = z;
    }

    // row max: max3-friendly tree + 2 shuffles
    float t0 = fmaxf(fmaxf(sc[0][0], sc[0][1]), sc[0][2]);
    float t1 = fmaxf(fmaxf(sc[0][3], sc[1][0]), sc[1][1]);
    float t2 = fmaxf(fmaxf(sc[1][2], sc[1][3]), sc[2][0]);
    float t3 = fmaxf(fmaxf(sc[2][1], sc[2][2]), sc[2][3]);
    float t4 = fmaxf(fmaxf(sc[3][0], sc[3][1]), sc[3][2]);
    float tm = fmaxf(fmaxf(fmaxf(t0, t1), t2), fmaxf(fmaxf(t3, t4), sc[3][3]));
    tm *= SCL;
    tm = fmaxf(tm, __shfl_xor(tm, 16, 64));
    tm = fmaxf(tm, __shfl_xor(tm, 32, 64));
    if (__any(tm > m_run + 8.0f)) {   // defer-max THR=8 (log2 domain)
      float mnew = fmaxf(m_run, tm);
      float corr = exp2_fast(m_run - mnew);
      #pragma unroll
      for (int dg = 0; dg < 4; ++dg) acc[dg] *= corr;
      accl *= corr;
      m_run = mnew;
    }
    // P = exp2(s*SCL - m); one b64 write per kt into own wave's Pl rows
    int qrow = wq + lm;
    #pragma unroll
    for (int kt = 0; kt < 4; ++kt) {
      float p0 = exp2_fast(fmaf(sc[kt][0], SCL, -m_run));
      float p1 = exp2_fast(fmaf(sc[kt][1], SCL, -m_run));
      float p2 = exp2_fast(fmaf(sc[kt][2], SCL, -m_run));
      float p3 = exp2_fast(fmaf(sc[kt][3], SCL, -m_run));
      half2v a = pkrtz(p0, p1), c = pkrtz(p2, p3);
      half4 h; h[0]=a[0]; h[1]=a[1]; h[2]=c[0]; h[3]=c[1];
      *(half4*)&Pl[swzi(qrow, kt * 16 + lg * 4)] = h;
    }

    // O^T += mfma(V^T, P^T); denominator via ones-MFMA
    #pragma unroll
    for (int ka = 0; ka < 2; ++ka) {
      half8 pf = *(half8*)&Pl[swzi(wq + lm, ka * 32 + lg * 8)];
      accl = mfma16(ones, pf, accl);
      #pragma unroll
      for (int dg = 0; dg < 4; ++dg) {
        half8 vf = *(half8*)&Vt[cur][swzv(dg * 16 + lm, ka * 32 + lg * 8)];
        acc[dg] = mfma16(vf, pf, acc[dg]);
      }
    }

    if (mt < 15) STORE_LDS(cur ^ 1);  // write next tile into other buffer
    __syncthreads();                  // one barrier per tile
    cur ^= 1;
  }

  // epilogue: accl[0] = sum over all keys for q=lm
  float inv = 1.f / accl[0];
  int n = n0 + wq + lm;
  _Float16* dst = O + ((size_t)(b * NH + hh) * NTOK + n) * 64;
  #pragma unroll
  for (int dg = 0; dg < 4; ++dg) {
    half2v p0 = pkrtz(acc[dg][0] * inv, acc[dg][1] * inv);
    half2v p1 = pkrtz(acc[dg][2] * inv, acc[dg][3] * inv);
    half4 h; h[0]=p0[0]; h[1]=p0[1]; h[2]=p1[0]; h[3]=p1[1];
    *(half4*)(dst + dg * 16 + lg * 4) = h;
  }
}

// ---------------------------------------------------------------------------
// projection: fp16 MFMA, A = attout fp16 [16384][256], B = pWh [co][ci],
// D[r][co] + bias -> f32 out.
// ---------------------------------------------------------------------------
__global__ __launch_bounds__(256) void proj_mfma(
    const _Float16* __restrict__ A, const _Float16* __restrict__ Wp,
    const float* __restrict__ bias, float* __restrict__ Out)
{
  const int rtile = blockIdx.x, ctile = blockIdx.y;
  __shared__ _Float16 As[128 * 64];
  __shared__ _Float16 Ws[64 * 64];
  const int t = threadIdx.x, wave = t >> 6, lane = t & 63;
  const int lm = lane & 15, lg = lane >> 4;
  const _Float16* Ab = A + (size_t)rtile * 128 * 256;
  const _Float16* Wb = Wp + ctile * 64 * 256;
  f32x4 acc[2][4];
  #pragma unroll
  for (int m = 0; m < 2; ++m)
    #pragma unroll
    for (int n = 0; n < 4; ++n) acc[m][n] = (f32x4){0.f, 0.f, 0.f, 0.f};

  for (int c0 = 0; c0 < 256; c0 += 64) {
    __syncthreads();
    #pragma unroll
    for (int i = 0; i < 4; ++i) {
      int u = t + i * 256; int r = u >> 3, ch = u & 7;
      *(half8*)&As[swzi(r, ch * 8)] = *(const half8*)&Ab[(size_t)r * 256 + c0 + ch * 8];
    }
    #pragma unroll
    for (int i = 0; i < 2; ++i) {
      int u = t + i * 256; int o = u >> 3, ch = u & 7;
      *(half8*)&Ws[swzi(o, ch * 8)] = *(const half8*)&Wb[o * 256 + c0 + ch * 8];
    }
    __syncthreads();
    #pragma unroll
    for (int kh = 0; kh < 2; ++kh) {
      half8 af[2], bf[4];
      #pragma unroll
      for (int m = 0; m < 2; ++m) af[m] = *(half8*)&As[swzi(wave * 32 + m * 16 + lm, kh * 32 + lg * 8)];
      #pragma unroll
      for (int n = 0; n < 4; ++n) bf[n] = *(half8*)&Ws[swzi(n * 16 + lm, kh * 32 + lg * 8)];
      #pragma unroll
      for (int m = 0; m < 2; ++m)
        #pragma unroll
        for (int n = 0; n < 4; ++n)
          acc[m][n] = mfma16(af[m], bf[n], acc[m][n]);
    }
  }
  float* Ob = Out + (size_t)rtile * 128 * 256 + ctile * 64;
  #pragma unroll
  for (int n = 0; n < 4; ++n) {
    float bia = bias[ctile * 64 + n * 16 + lm];
    #pragma unroll
    for (int m = 0; m < 2; ++m)
      #pragma unroll
      for (int rr = 0; rr < 4; ++rr)
        Ob[(size_t)(wave * 32 + m * 16 + lg * 4 + rr) * 256 + n * 16 + lm] =
            acc[m][n][rr] + bia;
  }
}

// ---------------------------------------------------------------------------
extern "C" void kernel_launch(void* const* d_in, const int* in_sizes, int n_in,
                              void* d_out, int out_size, void* d_ws, size_t ws_size,
                              hipStream_t stream) {
  const float* x        = (const float*)d_in[0];
  const float* y        = (const float*)d_in[1];
  const float* q_w      = (const float*)d_in[4];
  const float* q_gamma  = (const float*)d_in[5];
  const float* q_beta   = (const float*)d_in[6];
  const float* q_mean   = (const float*)d_in[7];
  const float* q_var    = (const float*)d_in[8];
  const float* kv_w     = (const float*)d_in[9];
  const float* kv_gamma = (const float*)d_in[10];
  const float* kv_beta  = (const float*)d_in[11];
  const float* kv_mean  = (const float*)d_in[12];
  const float* kv_var   = (const float*)d_in[13];
  const float* proj_w   = (const float*)d_in[14];
  const float* proj_b   = (const float*)d_in[15];
  float* out = (float*)d_out;

  _Float16* Xt   = (_Float16*)d_ws;                   // 4M halfs
  _Float16* Yt   = Xt   + (size_t)BB * NTOK * CC;     // 4M
  _Float16* qbn  = Yt   + (size_t)BB * NTOK * CC;     // 4M
  _Float16* kvbn = qbn  + (size_t)BB * CC * NTOK;     // 2M
  _Float16* aout = kvbn + (size_t)BB * CKV * NTOK;    // 4M
  _Float16* qWh  = aout + (size_t)BB * NH * NTOK * HD;
  _Float16* kWh  = qWh + 256 * 256;
  _Float16* pWh  = kWh + 128 * 256;
  float* qB2 = (float*)(pWh + 256 * 256);
  float* kB2 = qB2 + 256;

  pre_all<<<2688, 256, 0, stream>>>(
      x, y, q_w, q_gamma, q_beta, q_mean, q_var,
      kv_w, kv_gamma, kv_beta, kv_mean, kv_var, proj_w,
      Xt, Yt, qWh, qB2, kWh, kB2, pWh);
  conv_mfma_all<<<dim3(32, 6, BB), 256, 0, stream>>>(
      Xt, Yt, qWh, qB2, kWh, kB2, qbn, kvbn);
  attn_mfma5<<<dim3(32, NH, BB), 512, 0, stream>>>(qbn, kvbn, aout);
  proj_mfma<<<dim3(128, 4), 256, 0, stream>>>(aout, pWh, proj_b, out);
}